// Round 7
// baseline (277.798 us; speedup 1.0000x reference)
//
#include <hip/hip_runtime.h>
#include <math.h>

#define NCELL 1280
#define TAB_LO (-5.0f)
#define TAB_INVSTEP 128.0f
#define TAB_STEP 0.0078125f
#define EPSF 1e-8f
#define SCALE_128 0.08838834764831845f   // 1/sqrt(128)
#define GRID_MAIN 1024

// ---------------- table build kernel ----------------
// ws layout: ws[0] = max centroid; float4 cells at ws+16:
//   {bnd[lo] or +inf, cent[lo], cent[lo+1] (clamped), 0}
// Cell width 2^-7 = 0.0078 < min Lloyd-Max boundary spacing (~0.017 at center),
// so every cell contains at most one boundary -> single-compare correction valid.
__global__ __launch_bounds__(256) void build_table(const float* __restrict__ cent,
                                                   float* __restrict__ ws) {
    __shared__ float sc[256];
    __shared__ float sb[255];
    int tid = threadIdx.x;
    sc[tid] = cent[tid];
    __syncthreads();
    if (tid < 255) sb[tid] = 0.5f * (sc[tid] + sc[tid + 1]);
    __syncthreads();
    int k = blockIdx.x * 256 + tid;
    if (k < NCELL) {
        float edge = TAB_LO + (float)k * TAB_STEP;   // exact in f32 (pow2 step)
        int lo = 0, hi = 255;                        // lower_bound: count of bnd < edge
        while (lo < hi) {
            int mid = (lo + hi) >> 1;
            if (sb[mid] < edge) lo = mid + 1; else hi = mid;
        }
        float4 cl;
        cl.x = (lo < 255) ? sb[lo] : __int_as_float(0x7f800000);  // +inf
        cl.y = sc[lo];
        cl.z = (lo < 255) ? sc[lo + 1] : sc[255];
        cl.w = 0.0f;
        ((float4*)(ws + 16))[k] = cl;
    }
    if (blockIdx.x == 0 && tid == 0) {
        float m = sc[0];
        for (int i = 1; i < 256; ++i) m = fmaxf(m, sc[i]);
        ws[0] = m;
    }
}

// ---------------- cross-lane helpers (all on the VALU pipe, zero LDS ops) ----
__device__ __forceinline__ float dpp_xor1(float x) {   // quad_perm [1,0,3,2]
    int i = __float_as_int(x);
    return __int_as_float(__builtin_amdgcn_update_dpp(i, i, 0xB1, 0xF, 0xF, true));
}
__device__ __forceinline__ float dpp_xor2(float x) {   // quad_perm [2,3,0,1]
    int i = __float_as_int(x);
    return __int_as_float(__builtin_amdgcn_update_dpp(i, i, 0x4E, 0xF, 0xF, true));
}
// xor-4 exchange, VARIANT A — verified PASS in rounds 5/6 (absmax 0.0156).
//   banks 0,2 ((lane&4)==0) need partner i+4 -> row_shl:4, bank_mask 0x5
//   banks 1,3 ((lane&4)==4) need partner i-4 -> row_shr:4, bank_mask 0xA
__device__ __forceinline__ float dpp_xor4(float x) {
    int i = __float_as_int(x);
    int t = __builtin_amdgcn_update_dpp(i, i, 0x104, 0xF, 0x5, false); // row_shl:4 -> banks 0,2
    t = __builtin_amdgcn_update_dpp(t, i, 0x114, 0xF, 0xA, false);     // row_shr:4 -> banks 1,3
    return __int_as_float(t);
}

__device__ __forceinline__ float rsum8(float v) {
    v += dpp_xor1(v);
    v += dpp_xor2(v);
    v += dpp_xor4(v);
    return v;
}
__device__ __forceinline__ float rmax8(float v) {
    v = fmaxf(v, dpp_xor1(v));
    v = fmaxf(v, dpp_xor2(v));
    v = fmaxf(v, dpp_xor4(v));
    return v;
}

// FWHT-128: element j = c*32 + l*4 + e; within-lane stages h=1,2 (e bits) and
// h=32,64 (c bits); cross-lane stages h=4,8,16 via DPP xor 1,2,4.
__device__ __forceinline__ void fwht128(float v[16], float s1, float s2, float s4) {
#pragma unroll
    for (int c = 0; c < 4; ++c) {           // h=1, h=2 (radix-4)
        int b = c * 4;
        float a0 = v[b], a1 = v[b + 1], a2 = v[b + 2], a3 = v[b + 3];
        float t0 = a0 + a1, t1 = a0 - a1, t2 = a2 + a3, t3 = a2 - a3;
        v[b] = t0 + t2; v[b + 1] = t1 + t3; v[b + 2] = t0 - t2; v[b + 3] = t1 - t3;
    }
#pragma unroll
    for (int i = 0; i < 16; ++i) { float t = dpp_xor1(v[i]); v[i] = fmaf(s1, v[i], t); }  // h=4
#pragma unroll
    for (int i = 0; i < 16; ++i) { float t = dpp_xor2(v[i]); v[i] = fmaf(s2, v[i], t); }  // h=8
#pragma unroll
    for (int i = 0; i < 16; ++i) { float t = dpp_xor4(v[i]); v[i] = fmaf(s4, v[i], t); }  // h=16
#pragma unroll
    for (int e = 0; e < 4; ++e) {           // h=32, h=64 (radix-4 over c)
        float a0 = v[e], a1 = v[4 + e], a2 = v[8 + e], a3 = v[12 + e];
        float t0 = a0 + a1, t1 = a0 - a1, t2 = a2 + a3, t3 = a2 - a3;
        v[e] = t0 + t2; v[4 + e] = t1 + t3; v[8 + e] = t0 - t2; v[12 + e] = t1 - t3;
    }
}

// Fused cell: one ds_read_b128 per lookup, no dependent second read.
__device__ __forceinline__ float qlook(float u, const float4* sCell) {
    float t = (u - TAB_LO) * TAB_INVSTEP;
    int k = (int)t;
    k = k < 0 ? 0 : (k > NCELL - 1 ? NCELL - 1 : k);
    float4 cl = sCell[k];
    return (cl.x < u) ? cl.z : cl.y;   // searchsorted 'left' correction
}

__device__ __forceinline__ void load16(const float* __restrict__ p, int l, float v[16]) {
#pragma unroll
    for (int c = 0; c < 4; ++c) {
        float4 t4 = *(const float4*)(p + c * 32 + l * 4);
        v[c * 4 + 0] = t4.x; v[c * 4 + 1] = t4.y; v[c * 4 + 2] = t4.z; v[c * 4 + 3] = t4.w;
    }
}

// ---------------- main kernel ----------------
// 2-way ILP: each wave processes TWO independent 8-row sets (A and B) per
// iteration, phase-interleaved so every latency event (global load, LDS
// gather, DPP chain) has an independent twin to overlap with.
__global__ __launch_bounds__(256) void tq_main(const float* __restrict__ x,
                                               const float* __restrict__ signs,
                                               const float* __restrict__ ws,
                                               float* __restrict__ out,
                                               int ntiles) {
    __shared__ float4 sCell[NCELL];   // 20480 B
    int tid = threadIdx.x;
    const float4* wcell = (const float4*)(ws + 16);
    for (int i = tid; i < NCELL; i += 256) sCell[i] = wcell[i];
    float maxc = ws[0];
    __syncthreads();

    int lane = tid & 63;
    int wv = tid >> 6;      // wave in block: 0..3
    int g = lane >> 3;      // row within wave-half: 0..7
    int l = lane & 7;       // lane within row-group: 0..7
    float s1 = (l & 1) ? -1.0f : 1.0f;
    float s2 = (l & 2) ? -1.0f : 1.0f;
    float s4 = (l & 4) ? -1.0f : 1.0f;

    // this lane's 16 sign values (j = c*32 + l*4 + e)
    float sg[16];
    load16(signs, l, sg);

    for (int tile = blockIdx.x; tile < ntiles; tile += gridDim.x) {
        int base = tile * 64 + wv * 16 + g;          // block eats 64 rows/iter
        const float* xpA = x + (size_t)base * 128;
        const float* xpB = x + (size_t)(base + 8) * 128;
        float vA[16], vB[16];
        load16(xpA, l, vA);
        load16(xpB, l, vB);
        // ---- norm ----
        float ssA = 0.0f, ssB = 0.0f;
#pragma unroll
        for (int i = 0; i < 16; ++i) { ssA = fmaf(vA[i], vA[i], ssA); ssB = fmaf(vB[i], vB[i], ssB); }
        ssA = rsum8(ssA); ssB = rsum8(ssB);
        float normA = sqrtf(ssA) + EPSF, normB = sqrtf(ssB) + EPSF;
        float invnA = 1.0f / normA,      invnB = 1.0f / normB;
        // ---- rotate ----
#pragma unroll
        for (int i = 0; i < 16; ++i) { vA[i] = vA[i] * invnA * sg[i]; vB[i] = vB[i] * invnB * sg[i]; }
        fwht128(vA, s1, s2, s4);
        fwht128(vB, s1, s2, s4);
#pragma unroll
        for (int i = 0; i < 16; ++i) { vA[i] *= SCALE_128; vB[i] *= SCALE_128; }
        // ---- stats ----
        float mxA = 0.0f, smA = 0.0f, mxB = 0.0f, smB = 0.0f;
#pragma unroll
        for (int i = 0; i < 16; ++i) {
            float aA = fabsf(vA[i]); mxA = fmaxf(mxA, aA); smA += aA;
            float aB = fabsf(vB[i]); mxB = fmaxf(mxB, aB); smB += aB;
        }
        mxA = rmax8(mxA); mxB = rmax8(mxB);
        smA = rsum8(smA); smB = rsum8(smB);
        float meanA = smA * 0.0078125f + EPSF, meanB = smB * 0.0078125f + EPSF;
        float rmsA = mxA / maxc,               rmsB = mxB / maxc;
        bool spikyA = (mxA / meanA) > 5.0f,    spikyB = (mxB / meanB) > 5.0f;
        // ---- pass 1 ----
        float invdA = 1.0f / (rmsA + EPSF), invdB = 1.0f / (rmsB + EPSF);
        float dxrA = 0.0f, drrA = 0.0f, dxrB = 0.0f, drrB = 0.0f;
#pragma unroll
        for (int i = 0; i < 16; ++i) {
            float rA = qlook(vA[i] * invdA, sCell);
            float rB = qlook(vB[i] * invdB, sCell);
            dxrA = fmaf(vA[i], rA, dxrA); drrA = fmaf(rA, rA, drrA);
            dxrB = fmaf(vB[i], rB, dxrB); drrB = fmaf(rB, rB, drrB);
        }
        dxrA = rsum8(dxrA); drrA = rsum8(drrA);
        dxrB = rsum8(dxrB); drrB = rsum8(drrB);
        float g1A = dxrA / (drrA + EPSF), g1B = dxrB / (drrB + EPSF);
        // ---- pass 2 ----
        float invgA = 1.0f / (g1A + EPSF), invgB = 1.0f / (g1B + EPSF);
        float rrA[16], rrB[16];
        dxrA = 0.0f; drrA = 0.0f; dxrB = 0.0f; drrB = 0.0f;
#pragma unroll
        for (int i = 0; i < 16; ++i) {
            float rA = qlook(vA[i] * invgA, sCell);
            float rB = qlook(vB[i] * invgB, sCell);
            rrA[i] = rA; rrB[i] = rB;
            dxrA = fmaf(vA[i], rA, dxrA); drrA = fmaf(rA, rA, drrA);
            dxrB = fmaf(vB[i], rB, dxrB); drrB = fmaf(rB, rB, drrB);
        }
        dxrA = rsum8(dxrA); drrA = rsum8(drrA);
        dxrB = rsum8(dxrB); drrB = rsum8(drrB);
        float g2A = dxrA / (drrA + EPSF), g2B = dxrB / (drrB + EPSF);
        float gammaA = spikyA ? rmsA : g2A, gammaB = spikyB ? rmsB : g2B;
        if (spikyA) {   // rare: re-gather r1 for spiky rows
#pragma unroll
            for (int i = 0; i < 16; ++i) rrA[i] = qlook(vA[i] * invdA, sCell);
        }
        if (spikyB) {
#pragma unroll
            for (int i = 0; i < 16; ++i) rrB[i] = qlook(vB[i] * invdB, sCell);
        }
        // ---- reconstruct ----
#pragma unroll
        for (int i = 0; i < 16; ++i) { rrA[i] *= gammaA; rrB[i] *= gammaB; }
        fwht128(rrA, s1, s2, s4);
        fwht128(rrB, s1, s2, s4);
        float fscA = SCALE_128 * normA, fscB = SCALE_128 * normB;
        float* opA = out + (size_t)base * 128;
        float* opB = out + (size_t)(base + 8) * 128;
#pragma unroll
        for (int c = 0; c < 4; ++c) {
            float4 oA, oB;
            oA.x = rrA[c * 4 + 0] * sg[c * 4 + 0] * fscA;
            oA.y = rrA[c * 4 + 1] * sg[c * 4 + 1] * fscA;
            oA.z = rrA[c * 4 + 2] * sg[c * 4 + 2] * fscA;
            oA.w = rrA[c * 4 + 3] * sg[c * 4 + 3] * fscA;
            oB.x = rrB[c * 4 + 0] * sg[c * 4 + 0] * fscB;
            oB.y = rrB[c * 4 + 1] * sg[c * 4 + 1] * fscB;
            oB.z = rrB[c * 4 + 2] * sg[c * 4 + 2] * fscB;
            oB.w = rrB[c * 4 + 3] * sg[c * 4 + 3] * fscB;
            *(float4*)(opA + c * 32 + l * 4) = oA;
            *(float4*)(opB + c * 32 + l * 4) = oB;
        }
    }
}

extern "C" void kernel_launch(void* const* d_in, const int* in_sizes, int n_in,
                              void* d_out, int out_size, void* d_ws, size_t ws_size,
                              hipStream_t stream) {
    const float* x     = (const float*)d_in[0];
    const float* signs = (const float*)d_in[1];
    const float* cent  = (const float*)d_in[2];
    float* out = (float*)d_out;
    float* ws  = (float*)d_ws;

    int nrows  = in_sizes[0] / 128;
    int ntiles = nrows / 64;     // 64 rows per block-iteration (4 waves x 2 x 8 rows)

    build_table<<<(NCELL + 255) / 256, 256, 0, stream>>>(cent, ws);
    int grid = ntiles < GRID_MAIN ? ntiles : GRID_MAIN;
    tq_main<<<grid, 256, 0, stream>>>(x, signs, ws, out, ntiles);
}